// Round 2
// baseline (490.911 us; speedup 1.0000x reference)
//
#include <hip/hip_runtime.h>

#define S     2048
#define D     64
#define NH    12
#define NB    2
#define BQ    32            // query rows per block
#define NW    8             // waves per block
#define QT    (S/BQ)        // 64 q-tiles per (b,h)
#define NBH   (NB*NH)       // 24
#define NBLK  (NBH*QT)      // 1536
#define OUTSZ ((size_t)NBH*S*D)   // 3145728 elements per out tensor

typedef __attribute__((ext_vector_type(8))) short short8;
typedef __attribute__((ext_vector_type(4))) float f32x4;

__device__ __forceinline__ unsigned short f2bf(float x){
  unsigned u = __builtin_bit_cast(unsigned, x);
  u += 0x7fffu + ((u >> 16) & 1u);       // RTNE
  return (unsigned short)(u >> 16);
}
__device__ __forceinline__ float bf2f(unsigned short h){
  unsigned u = ((unsigned)h) << 16;
  return __builtin_bit_cast(float, u);
}
__device__ __forceinline__ short8 pack8(const float4& a, const float4& b, float sc){
  short8 r;
  r[0]=(short)f2bf(a.x*sc); r[1]=(short)f2bf(a.y*sc);
  r[2]=(short)f2bf(a.z*sc); r[3]=(short)f2bf(a.w*sc);
  r[4]=(short)f2bf(b.x*sc); r[5]=(short)f2bf(b.y*sc);
  r[6]=(short)f2bf(b.z*sc); r[7]=(short)f2bf(b.w*sc);
  return r;
}

// LDS e-tile byte offset with XOR swizzle (row-major [BQ][S] bf16, row stride 4096B).
// Without swizzle, lanes reading different rows at the same k hit one bank (32-way).
__device__ __forceinline__ int eoff(int row, int key){
  return ((row << 12) | (key << 1)) ^ ((row & 7) << 4);
}

__global__ __launch_bounds__(512) void cattn_kernel(
    const float* __restrict__ q_real, const float* __restrict__ q_imag,
    const float* __restrict__ k_real, const float* __restrict__ k_imag,
    const float* __restrict__ v_real, const float* __restrict__ v_imag,
    const int*   __restrict__ mask,   float* __restrict__ out)
{
  extern __shared__ __align__(16) char lds[];      // [BQ*S*2] e (bf16, swizzled)
  float* l_lds = (float*)(lds + (size_t)BQ*S*2);   // [NW][BQ] per-wave row sums
  float* l_inv = l_lds + NW*BQ;                    // [BQ] 1/rowsum

  // XCD-aware bijective swizzle: 1536 = 8 * 192
  int bid = blockIdx.x;
  int swz = (bid & 7) * (NBLK/8) + (bid >> 3);
  int bh    = swz / QT;
  int qt    = swz % QT;
  int b0    = bh / NH;
  int qbase = qt * BQ;

  int tid  = threadIdx.x;
  int w    = tid >> 6;
  int lane = tid & 63;
  int col  = lane & 15;    // MFMA "col"/"row=l&15" index
  int kg   = lane >> 4;    // 0..3

  const size_t bhSD = (size_t)bh * S * D;

  // ---- Q fragments: A_r = [qr,qi]/8, A_i = [qi,-qr]/8, K=128 over 4 chunks of 32
  short8 a_r[2][4], a_i[2][4];
  #pragma unroll
  for (int m = 0; m < 2; m++){
    const float* qrp = q_real + bhSD + (size_t)(qbase + m*16 + col) * D;
    const float* qip = q_imag + bhSD + (size_t)(qbase + m*16 + col) * D;
    #pragma unroll
    for (int h = 0; h < 2; h++){
      int d0 = h*32 + kg*8;
      float4 r0 = *(const float4*)(qrp + d0);
      float4 r1 = *(const float4*)(qrp + d0 + 4);
      float4 i0 = *(const float4*)(qip + d0);
      float4 i1 = *(const float4*)(qip + d0 + 4);
      a_r[m][h]   = pack8(r0, r1,  0.125f);
      a_r[m][2+h] = pack8(i0, i1,  0.125f);
      a_i[m][h]   = a_r[m][2+h];
      a_i[m][2+h] = pack8(r0, r1, -0.125f);
    }
  }

  // ---- Phase 1: scores + exp + row sums; wave w owns keys [w*256, w*256+256)
  float lsum[2][4] = {{0.f,0.f,0.f,0.f},{0.f,0.f,0.f,0.f}};
  const int* mrow = mask + (size_t)b0 * S * S;

  for (int t = 0; t < 16; t++){
    int n0  = w*256 + t*16;
    int key = n0 + col;
    const float* krp = k_real + bhSD + (size_t)key * D;
    const float* kip = k_imag + bhSD + (size_t)key * D;
    short8 bv[4];
    #pragma unroll
    for (int h = 0; h < 2; h++){
      int d0 = h*32 + kg*8;
      float4 r0 = *(const float4*)(krp + d0);
      float4 r1 = *(const float4*)(krp + d0 + 4);
      float4 i0 = *(const float4*)(kip + d0);
      float4 i1 = *(const float4*)(kip + d0 + 4);
      bv[h]   = pack8(r0, r1, 1.f);
      bv[2+h] = pack8(i0, i1, 1.f);
    }
    f32x4 accr[2], acci[2];
    #pragma unroll
    for (int m = 0; m < 2; m++){ accr[m] = (f32x4)(0.f); acci[m] = (f32x4)(0.f); }
    #pragma unroll
    for (int m = 0; m < 2; m++)
      #pragma unroll
      for (int kc = 0; kc < 4; kc++){
        accr[m] = __builtin_amdgcn_mfma_f32_16x16x32_bf16(a_r[m][kc], bv[kc], accr[m], 0, 0, 0);
        acci[m] = __builtin_amdgcn_mfma_f32_16x16x32_bf16(a_i[m][kc], bv[kc], acci[m], 0, 0, 0);
      }
    #pragma unroll
    for (int m = 0; m < 2; m++){
      int qrow_g = qbase + m*16 + kg*4;
      #pragma unroll
      for (int r = 0; r < 4; r++){
        float ar = accr[m][r], ai = acci[m][r];
        float s  = sqrtf(ar*ar + ai*ai);
        int  mv  = mrow[(size_t)(qrow_g + r) * S + key];
        float ex = __expf(s);
        float e  = mv ? ex : 0.f;          // masked -> exp(-1e9)=0 exactly
        lsum[m][r] += e;
        int row = m*16 + kg*4 + r;
        *(unsigned short*)(lds + eoff(row, key)) = f2bf(e);
      }
    }
  }

  // reduce row sums across the 16 lanes of each kg-group, then across waves
  #pragma unroll
  for (int m = 0; m < 2; m++)
    #pragma unroll
    for (int r = 0; r < 4; r++){
      float v = lsum[m][r];
      v += __shfl_xor(v, 1); v += __shfl_xor(v, 2);
      v += __shfl_xor(v, 4); v += __shfl_xor(v, 8);
      lsum[m][r] = v;
    }
  if (col == 0){
    #pragma unroll
    for (int m = 0; m < 2; m++)
      #pragma unroll
      for (int r = 0; r < 4; r++)
        l_lds[w*BQ + m*16 + kg*4 + r] = lsum[m][r];
  }
  __syncthreads();
  if (tid < BQ){
    float t = 0.f;
    #pragma unroll
    for (int ww = 0; ww < NW; ww++) t += l_lds[ww*BQ + tid];
    l_inv[tid] = 1.f / t;
  }
  __syncthreads();

  // ---- Phase 2: PV. wave w -> 16 output cols: ri = w>>2, dbase = (w&3)*16
  {
    int ri    = w >> 2;
    int dbase = (w & 3) * 16;
    const float* vp = (ri ? v_imag : v_real) + bhSD;
    f32x4 acc[2]; acc[0] = (f32x4)(0.f); acc[1] = (f32x4)(0.f);
    for (int c = 0; c < 64; c++){
      int k0 = c*32 + kg*8;
      short8 bv;
      #pragma unroll
      for (int j = 0; j < 8; j++)
        bv[j] = (short)f2bf(vp[(size_t)(k0 + j) * D + dbase + col]);
      #pragma unroll
      for (int m = 0; m < 2; m++){
        int row = m*16 + col;
        short8 av = *(const short8*)(lds + eoff(row, k0));
        acc[m] = __builtin_amdgcn_mfma_f32_16x16x32_bf16(av, bv, acc[m], 0, 0, 0);
      }
    }
    float* outp = out + (ri ? OUTSZ : 0) + bhSD;
    #pragma unroll
    for (int m = 0; m < 2; m++)
      #pragma unroll
      for (int r = 0; r < 4; r++){
        int row = m*16 + kg*4 + r;
        outp[(size_t)(qbase + row) * D + dbase + col] = acc[m][r] * l_inv[row];
      }
  }

  // ---- Phase 3: write normalized attn (p = e / l), coalesced float4 x2 per thread
  {
    float* attnp = out + 2*OUTSZ + (size_t)bh*S*S + (size_t)qbase*S;
    #pragma unroll
    for (int g = 0; g < 16; g++){
      int flat = g*4096 + tid*8;
      int row  = flat >> 11;
      int k    = flat & 2047;
      short8 ev = *(const short8*)(lds + eoff(row, k));
      float inv = l_inv[row];
      float4 o0, o1;
      o0.x = bf2f((unsigned short)ev[0]) * inv;
      o0.y = bf2f((unsigned short)ev[1]) * inv;
      o0.z = bf2f((unsigned short)ev[2]) * inv;
      o0.w = bf2f((unsigned short)ev[3]) * inv;
      o1.x = bf2f((unsigned short)ev[4]) * inv;
      o1.y = bf2f((unsigned short)ev[5]) * inv;
      o1.z = bf2f((unsigned short)ev[6]) * inv;
      o1.w = bf2f((unsigned short)ev[7]) * inv;
      *(float4*)(attnp + (size_t)row*S + k)     = o0;
      *(float4*)(attnp + (size_t)row*S + k + 4) = o1;
    }
  }
}

extern "C" void kernel_launch(void* const* d_in, const int* in_sizes, int n_in,
                              void* d_out, int out_size, void* d_ws, size_t ws_size,
                              hipStream_t stream)
{
  const float* qr = (const float*)d_in[0];
  const float* qi = (const float*)d_in[1];
  const float* kr = (const float*)d_in[2];
  const float* ki = (const float*)d_in[3];
  const float* vr = (const float*)d_in[4];
  const float* vi = (const float*)d_in[5];
  const int*   mk = (const int*)d_in[6];
  float* out = (float*)d_out;

  size_t ldsbytes = (size_t)BQ*S*2 + (size_t)NW*BQ*4 + (size_t)BQ*4;  // 132224 B
  cattn_kernel<<<dim3(NBLK), dim3(512), ldsbytes, stream>>>(qr, qi, kr, ki, vr, vi, mk, out);
}

// Round 3
// 434.313 us; speedup vs baseline: 1.1303x; 1.1303x over previous
//
#include <hip/hip_runtime.h>

#define S     2048
#define D     64
#define NH    12
#define NB    2
#define BQ    32
#define QT    (S/BQ)        // 64
#define NBH   (NB*NH)       // 24
#define NBLK  (NBH*QT)      // 1536
#define OUTSZ ((size_t)NBH*S*D)

// workspace layout (bytes)
#define KCAT_OFF  0
#define KCAT_SZ   ((size_t)NBH*S*128*2)        // 12582912
#define VT_OFF    (KCAT_OFF + KCAT_SZ)
#define VT_SZ     ((size_t)2*NBH*D*S*2)        // 12582912
#define MT_OFF    (VT_OFF + VT_SZ)
#define MT_SZ     ((size_t)NB*S*S)             // 8388608
#define WS_NEED   (MT_OFF + MT_SZ)             // 33554432

typedef __attribute__((ext_vector_type(8))) short short8;
typedef __attribute__((ext_vector_type(4))) short s4v;
typedef __attribute__((ext_vector_type(4))) float f32x4;

__device__ __forceinline__ unsigned short f2bf(float x){
  unsigned u = __builtin_bit_cast(unsigned, x);
  u += 0x7fffu + ((u >> 16) & 1u);       // RTNE
  return (unsigned short)(u >> 16);
}
__device__ __forceinline__ float bf2f(unsigned short h){
  unsigned u = ((unsigned)h) << 16;
  return __builtin_bit_cast(float, u);
}
__device__ __forceinline__ short8 pack8(const float4& a, const float4& b, float sc){
  short8 r;
  r[0]=(short)f2bf(a.x*sc); r[1]=(short)f2bf(a.y*sc);
  r[2]=(short)f2bf(a.z*sc); r[3]=(short)f2bf(a.w*sc);
  r[4]=(short)f2bf(b.x*sc); r[5]=(short)f2bf(b.y*sc);
  r[6]=(short)f2bf(b.z*sc); r[7]=(short)f2bf(b.w*sc);
  return r;
}
__device__ __forceinline__ int eoff(int row, int key){
  return ((row << 12) | (key << 1)) ^ ((row & 7) << 4);
}

// ---------------- conversion pre-kernels ----------------

// K -> bf16 concat rows [NBH][S][128] (kr|ki)
__global__ __launch_bounds__(256) void conv_k(const float* __restrict__ kr,
                                              const float* __restrict__ ki,
                                              unsigned short* __restrict__ kcat){
  int idx = blockIdx.x*256 + threadIdx.x;          // one short8 per thread
  int d8  = (idx & 15) * 8;
  int ri  = idx >> 4;                               // bh*2048+s
  const float* src = (d8 < 64 ? kr + (size_t)ri*64 + d8 : ki + (size_t)ri*64 + (d8-64));
  float4 a = *(const float4*)(src);
  float4 b = *(const float4*)(src + 4);
  *(short8*)(kcat + (size_t)ri*128 + d8) = pack8(a, b, 1.f);
}

// V -> transposed bf16 [2][NBH][D][S]
__global__ __launch_bounds__(256) void conv_v(const float* __restrict__ vr,
                                              const float* __restrict__ vi,
                                              unsigned short* __restrict__ vt){
  __shared__ unsigned short tile[64][65];
  int bid = blockIdx.x;
  int ri  = bid / (NBH*32);
  int rem = bid % (NBH*32);
  int bh  = rem / 32;
  int s0  = (rem % 32) * 64;
  const float* vp = (ri ? vi : vr) + (size_t)bh*S*D;
  int t = threadIdx.x;
  #pragma unroll
  for (int it = 0; it < 4; it++){
    int row = (t >> 4) + it*16;
    int c4  = (t & 15) * 4;
    float4 v = *(const float4*)(vp + (size_t)(s0+row)*D + c4);
    tile[c4+0][row] = f2bf(v.x);
    tile[c4+1][row] = f2bf(v.y);
    tile[c4+2][row] = f2bf(v.z);
    tile[c4+3][row] = f2bf(v.w);
  }
  __syncthreads();
  unsigned short* dst = vt + ((size_t)(ri*NBH + bh) * D) * S;
  #pragma unroll
  for (int it = 0; it < 4; it++){
    int d  = (t >> 4) + it*16;
    int s4 = (t & 15) * 4;
    s4v o;
    o[0]=(short)tile[d][s4+0]; o[1]=(short)tile[d][s4+1];
    o[2]=(short)tile[d][s4+2]; o[3]=(short)tile[d][s4+3];
    *(s4v*)(dst + (size_t)d*S + s0 + s4) = o;
  }
}

// mask -> transposed uchar [NB][S][S]: mt[b][key][row] = mask[b][row][key]
__global__ __launch_bounds__(256) void conv_m(const int* __restrict__ mask,
                                              unsigned char* __restrict__ mt){
  __shared__ unsigned char tile[64][68];
  int bid = blockIdx.x;
  int b   = bid / 1024;
  int rem = bid % 1024;
  int r0  = (rem / 32) * 64;
  int k0  = (rem % 32) * 64;
  int t = threadIdx.x;
  const int* mp = mask + (size_t)b*S*S;
  #pragma unroll
  for (int it = 0; it < 4; it++){
    int row = (t >> 4) + it*16;
    int c4  = (t & 15) * 4;
    int4 v = *(const int4*)(mp + (size_t)(r0+row)*S + k0 + c4);
    tile[c4+0][row] = (unsigned char)v.x;
    tile[c4+1][row] = (unsigned char)v.y;
    tile[c4+2][row] = (unsigned char)v.z;
    tile[c4+3][row] = (unsigned char)v.w;
  }
  __syncthreads();
  unsigned char* dst = mt + (size_t)b*S*S;
  #pragma unroll
  for (int it = 0; it < 4; it++){
    int k  = (t >> 4) + it*16;
    int r4 = (t & 15) * 4;
    unsigned u = (unsigned)tile[k][r4+0] | ((unsigned)tile[k][r4+1]<<8)
               | ((unsigned)tile[k][r4+2]<<16) | ((unsigned)tile[k][r4+3]<<24);
    *(unsigned*)(dst + (size_t)(k0+k)*S + r0 + r4) = u;
  }
}

// ---------------- main kernel: 1024 threads / 16 waves ----------------

__global__ __launch_bounds__(1024) void cattn_fast(
    const float* __restrict__ q_real, const float* __restrict__ q_imag,
    const unsigned short* __restrict__ kcat,
    const unsigned short* __restrict__ vt,
    const unsigned char*  __restrict__ mt,
    float* __restrict__ out)
{
  extern __shared__ __align__(16) char lds[];      // [BQ*S*2] e (bf16, swizzled)
  float* l_lds = (float*)(lds + (size_t)BQ*S*2);   // [16][BQ]
  float* l_inv = l_lds + 16*BQ;                    // [BQ]

  int bid = blockIdx.x;
  int swz = (bid & 7) * (NBLK/8) + (bid >> 3);     // XCD swizzle, 1536 = 8*192
  int bh    = swz / QT;
  int qt    = swz % QT;
  int b0    = bh / NH;
  int qbase = qt * BQ;

  int tid  = threadIdx.x;
  int w    = tid >> 6;       // 0..15
  int lane = tid & 63;
  int col  = lane & 15;
  int kg   = lane >> 4;

  const size_t bhSD = (size_t)bh * S * D;

  // Q fragments: A_r = [qr,qi]/8, A_i = [qi,-qr]/8 (K=128 over 4 chunks of 32)
  short8 a_r[2][4], a_i[2][4];
  #pragma unroll
  for (int m = 0; m < 2; m++){
    const float* qrp = q_real + bhSD + (size_t)(qbase + m*16 + col) * D;
    const float* qip = q_imag + bhSD + (size_t)(qbase + m*16 + col) * D;
    #pragma unroll
    for (int h = 0; h < 2; h++){
      int d0 = h*32 + kg*8;
      float4 r0 = *(const float4*)(qrp + d0);
      float4 r1 = *(const float4*)(qrp + d0 + 4);
      float4 i0 = *(const float4*)(qip + d0);
      float4 i1 = *(const float4*)(qip + d0 + 4);
      a_r[m][h]   = pack8(r0, r1,  0.125f);
      a_r[m][2+h] = pack8(i0, i1,  0.125f);
      a_i[m][h]   = a_r[m][2+h];
      a_i[m][2+h] = pack8(r0, r1, -0.125f);
    }
  }

  // ---- Phase 1: wave w owns keys [w*128, w*128+128)
  float lsum[2][4] = {{0.f,0.f,0.f,0.f},{0.f,0.f,0.f,0.f}};

  for (int t = 0; t < 8; t++){
    int key = w*128 + t*16 + col;
    const unsigned short* krow = kcat + ((size_t)bh*S + key) * 128;
    short8 bv[4];
    #pragma unroll
    for (int kc = 0; kc < 4; kc++)
      bv[kc] = *(const short8*)(krow + kc*32 + kg*8);

    const unsigned char* mrow = mt + (size_t)b0*S*S + (size_t)key*S + qbase;
    unsigned um0 = *(const unsigned*)(mrow + kg*4);
    unsigned um1 = *(const unsigned*)(mrow + 16 + kg*4);

    f32x4 accr[2], acci[2];
    #pragma unroll
    for (int m = 0; m < 2; m++){ accr[m] = (f32x4)(0.f); acci[m] = (f32x4)(0.f); }
    #pragma unroll
    for (int m = 0; m < 2; m++)
      #pragma unroll
      for (int kc = 0; kc < 4; kc++){
        accr[m] = __builtin_amdgcn_mfma_f32_16x16x32_bf16(a_r[m][kc], bv[kc], accr[m], 0, 0, 0);
        acci[m] = __builtin_amdgcn_mfma_f32_16x16x32_bf16(a_i[m][kc], bv[kc], acci[m], 0, 0, 0);
      }
    #pragma unroll
    for (int m = 0; m < 2; m++){
      unsigned um = m ? um1 : um0;
      #pragma unroll
      for (int r = 0; r < 4; r++){
        float ar = accr[m][r], ai = acci[m][r];
        float s  = sqrtf(ar*ar + ai*ai);
        float ex = __expf(s);
        float e  = ((um >> (8*r)) & 1u) ? ex : 0.f;
        lsum[m][r] += e;
        *(unsigned short*)(lds + eoff(m*16 + kg*4 + r, key)) = f2bf(e);
      }
    }
  }

  // row-sum reduce: 16 lanes in group, then across 16 waves
  #pragma unroll
  for (int m = 0; m < 2; m++)
    #pragma unroll
    for (int r = 0; r < 4; r++){
      float v = lsum[m][r];
      v += __shfl_xor(v, 1); v += __shfl_xor(v, 2);
      v += __shfl_xor(v, 4); v += __shfl_xor(v, 8);
      lsum[m][r] = v;
    }
  if (col == 0){
    #pragma unroll
    for (int m = 0; m < 2; m++)
      #pragma unroll
      for (int r = 0; r < 4; r++)
        l_lds[w*BQ + m*16 + kg*4 + r] = lsum[m][r];
  }
  __syncthreads();
  if (tid < BQ){
    float t = 0.f;
    #pragma unroll
    for (int ww = 0; ww < 16; ww++) t += l_lds[ww*BQ + tid];
    l_inv[tid] = 1.f / t;
  }
  __syncthreads();

  // ---- Phase 2: PV. wave -> (ri = w>>3, dgroup = (w>>1)&3, m = w&1)
  {
    int m     = w & 1;
    int dbase = ((w >> 1) & 3) * 16;
    int ri    = w >> 3;
    const unsigned short* vrow = vt + ((size_t)(ri*NBH + bh) * D + dbase + col) * S;
    f32x4 acc = (f32x4)(0.f);
    for (int c = 0; c < 64; c++){
      int k0 = c*32 + kg*8;
      short8 bv = *(const short8*)(vrow + k0);
      short8 av = *(const short8*)(lds + eoff(m*16 + col, k0));
      acc = __builtin_amdgcn_mfma_f32_16x16x32_bf16(av, bv, acc, 0, 0, 0);
    }
    float* outp = out + (ri ? OUTSZ : 0) + bhSD;
    #pragma unroll
    for (int r = 0; r < 4; r++){
      int row = m*16 + kg*4 + r;
      outp[(size_t)(qbase + row) * D + dbase + col] = acc[r] * l_inv[row];
    }
  }

  // ---- Phase 3: attn = e / l, coalesced float4 x2 per thread
  {
    float* attnp = out + 2*OUTSZ + (size_t)bh*S*S + (size_t)qbase*S;
    #pragma unroll
    for (int g = 0; g < 8; g++){
      int flat = g*8192 + tid*8;
      int row  = flat >> 11;
      int k    = flat & 2047;
      short8 ev = *(const short8*)(lds + eoff(row, k));
      float inv = l_inv[row];
      float4 o0, o1;
      o0.x = bf2f((unsigned short)ev[0]) * inv;
      o0.y = bf2f((unsigned short)ev[1]) * inv;
      o0.z = bf2f((unsigned short)ev[2]) * inv;
      o0.w = bf2f((unsigned short)ev[3]) * inv;
      o1.x = bf2f((unsigned short)ev[4]) * inv;
      o1.y = bf2f((unsigned short)ev[5]) * inv;
      o1.z = bf2f((unsigned short)ev[6]) * inv;
      o1.w = bf2f((unsigned short)ev[7]) * inv;
      *(float4*)(attnp + (size_t)row*S + k)     = o0;
      *(float4*)(attnp + (size_t)row*S + k + 4) = o1;
    }
  }
}

// ---------------- fallback (round-2 kernel, used if ws too small) ----------------

__global__ __launch_bounds__(512) void cattn_kernel(
    const float* __restrict__ q_real, const float* __restrict__ q_imag,
    const float* __restrict__ k_real, const float* __restrict__ k_imag,
    const float* __restrict__ v_real, const float* __restrict__ v_imag,
    const int*   __restrict__ mask,   float* __restrict__ out)
{
  extern __shared__ __align__(16) char lds[];
  float* l_lds = (float*)(lds + (size_t)BQ*S*2);
  float* l_inv = l_lds + 8*BQ;

  int bid = blockIdx.x;
  int swz = (bid & 7) * (NBLK/8) + (bid >> 3);
  int bh    = swz / QT;
  int qt    = swz % QT;
  int b0    = bh / NH;
  int qbase = qt * BQ;

  int tid  = threadIdx.x;
  int w    = tid >> 6;
  int lane = tid & 63;
  int col  = lane & 15;
  int kg   = lane >> 4;

  const size_t bhSD = (size_t)bh * S * D;

  short8 a_r[2][4], a_i[2][4];
  #pragma unroll
  for (int m = 0; m < 2; m++){
    const float* qrp = q_real + bhSD + (size_t)(qbase + m*16 + col) * D;
    const float* qip = q_imag + bhSD + (size_t)(qbase + m*16 + col) * D;
    #pragma unroll
    for (int h = 0; h < 2; h++){
      int d0 = h*32 + kg*8;
      float4 r0 = *(const float4*)(qrp + d0);
      float4 r1 = *(const float4*)(qrp + d0 + 4);
      float4 i0 = *(const float4*)(qip + d0);
      float4 i1 = *(const float4*)(qip + d0 + 4);
      a_r[m][h]   = pack8(r0, r1,  0.125f);
      a_r[m][2+h] = pack8(i0, i1,  0.125f);
      a_i[m][h]   = a_r[m][2+h];
      a_i[m][2+h] = pack8(r0, r1, -0.125f);
    }
  }

  float lsum[2][4] = {{0.f,0.f,0.f,0.f},{0.f,0.f,0.f,0.f}};
  const int* mrow = mask + (size_t)b0 * S * S;

  for (int t = 0; t < 16; t++){
    int key = w*256 + t*16 + col;
    const float* krp = k_real + bhSD + (size_t)key * D;
    const float* kip = k_imag + bhSD + (size_t)key * D;
    short8 bv[4];
    #pragma unroll
    for (int h = 0; h < 2; h++){
      int d0 = h*32 + kg*8;
      float4 r0 = *(const float4*)(krp + d0);
      float4 r1 = *(const float4*)(krp + d0 + 4);
      float4 i0 = *(const float4*)(kip + d0);
      float4 i1 = *(const float4*)(kip + d0 + 4);
      bv[h]   = pack8(r0, r1, 1.f);
      bv[2+h] = pack8(i0, i1, 1.f);
    }
    f32x4 accr[2], acci[2];
    #pragma unroll
    for (int m = 0; m < 2; m++){ accr[m] = (f32x4)(0.f); acci[m] = (f32x4)(0.f); }
    #pragma unroll
    for (int m = 0; m < 2; m++)
      #pragma unroll
      for (int kc = 0; kc < 4; kc++){
        accr[m] = __builtin_amdgcn_mfma_f32_16x16x32_bf16(a_r[m][kc], bv[kc], accr[m], 0, 0, 0);
        acci[m] = __builtin_amdgcn_mfma_f32_16x16x32_bf16(a_i[m][kc], bv[kc], acci[m], 0, 0, 0);
      }
    #pragma unroll
    for (int m = 0; m < 2; m++){
      int qrow_g = qbase + m*16 + kg*4;
      #pragma unroll
      for (int r = 0; r < 4; r++){
        float ar = accr[m][r], ai = acci[m][r];
        float s  = sqrtf(ar*ar + ai*ai);
        int  mv  = mrow[(size_t)(qrow_g + r) * S + key];
        float ex = __expf(s);
        float e  = mv ? ex : 0.f;
        lsum[m][r] += e;
        *(unsigned short*)(lds + eoff(m*16 + kg*4 + r, key)) = f2bf(e);
      }
    }
  }

  #pragma unroll
  for (int m = 0; m < 2; m++)
    #pragma unroll
    for (int r = 0; r < 4; r++){
      float v = lsum[m][r];
      v += __shfl_xor(v, 1); v += __shfl_xor(v, 2);
      v += __shfl_xor(v, 4); v += __shfl_xor(v, 8);
      lsum[m][r] = v;
    }
  if (col == 0){
    #pragma unroll
    for (int m = 0; m < 2; m++)
      #pragma unroll
      for (int r = 0; r < 4; r++)
        l_lds[w*BQ + m*16 + kg*4 + r] = lsum[m][r];
  }
  __syncthreads();
  if (tid < BQ){
    float t = 0.f;
    #pragma unroll
    for (int ww = 0; ww < 8; ww++) t += l_lds[ww*BQ + tid];
    l_inv[tid] = 1.f / t;
  }
  __syncthreads();

  {
    int ri    = w >> 2;
    int dbase = (w & 3) * 16;
    const float* vp = (ri ? v_imag : v_real) + bhSD;
    f32x4 acc[2]; acc[0] = (f32x4)(0.f); acc[1] = (f32x4)(0.f);
    for (int c = 0; c < 64; c++){
      int k0 = c*32 + kg*8;
      short8 bv;
      #pragma unroll
      for (int j = 0; j < 8; j++)
        bv[j] = (short)f2bf(vp[(size_t)(k0 + j) * D + dbase + col]);
      #pragma unroll
      for (int m = 0; m < 2; m++){
        short8 av = *(const short8*)(lds + eoff(m*16 + col, k0));
        acc[m] = __builtin_amdgcn_mfma_f32_16x16x32_bf16(av, bv, acc[m], 0, 0, 0);
      }
    }
    float* outp = out + (ri ? OUTSZ : 0) + bhSD;
    #pragma unroll
    for (int m = 0; m < 2; m++)
      #pragma unroll
      for (int r = 0; r < 4; r++){
        int row = m*16 + kg*4 + r;
        outp[(size_t)(qbase + row) * D + dbase + col] = acc[m][r] * l_inv[row];
      }
  }

  {
    float* attnp = out + 2*OUTSZ + (size_t)bh*S*S + (size_t)qbase*S;
    #pragma unroll
    for (int g = 0; g < 16; g++){
      int flat = g*4096 + tid*8;
      int row  = flat >> 11;
      int k    = flat & 2047;
      short8 ev = *(const short8*)(lds + eoff(row, k));
      float inv = l_inv[row];
      float4 o0, o1;
      o0.x = bf2f((unsigned short)ev[0]) * inv;
      o0.y = bf2f((unsigned short)ev[1]) * inv;
      o0.z = bf2f((unsigned short)ev[2]) * inv;
      o0.w = bf2f((unsigned short)ev[3]) * inv;
      o1.x = bf2f((unsigned short)ev[4]) * inv;
      o1.y = bf2f((unsigned short)ev[5]) * inv;
      o1.z = bf2f((unsigned short)ev[6]) * inv;
      o1.w = bf2f((unsigned short)ev[7]) * inv;
      *(float4*)(attnp + (size_t)row*S + k)     = o0;
      *(float4*)(attnp + (size_t)row*S + k + 4) = o1;
    }
  }
}

extern "C" void kernel_launch(void* const* d_in, const int* in_sizes, int n_in,
                              void* d_out, int out_size, void* d_ws, size_t ws_size,
                              hipStream_t stream)
{
  const float* qr = (const float*)d_in[0];
  const float* qi = (const float*)d_in[1];
  const float* kr = (const float*)d_in[2];
  const float* ki = (const float*)d_in[3];
  const float* vr = (const float*)d_in[4];
  const float* vi = (const float*)d_in[5];
  const int*   mk = (const int*)d_in[6];
  float* out = (float*)d_out;

  if (ws_size >= WS_NEED){
    unsigned short* kcat = (unsigned short*)((char*)d_ws + KCAT_OFF);
    unsigned short* vt   = (unsigned short*)((char*)d_ws + VT_OFF);
    unsigned char*  mt   = (unsigned char*)((char*)d_ws + MT_OFF);
    conv_k<<<dim3(NBH*S*128/8/256), dim3(256), 0, stream>>>(kr, ki, kcat);
    conv_v<<<dim3(2*NBH*32),        dim3(256), 0, stream>>>(vr, vi, vt);
    conv_m<<<dim3(NB*32*32),        dim3(256), 0, stream>>>(mk, mt);
    size_t ldsb = (size_t)BQ*S*2 + (size_t)16*BQ*4 + (size_t)BQ*4;   // 133248
    cattn_fast<<<dim3(NBLK), dim3(1024), ldsb, stream>>>(qr, qi, kcat, vt, mt, out);
  } else {
    size_t ldsb = (size_t)BQ*S*2 + (size_t)8*BQ*4 + (size_t)BQ*4;
    cattn_kernel<<<dim3(NBLK), dim3(512), ldsb, stream>>>(qr, qi, kr, ki, vr, vi, mk, out);
  }
}